// Round 15
// baseline (107.234 us; speedup 1.0000x reference)
//
#include <hip/hip_runtime.h>

#define B_ 32
#define P_ 4096
#define Q_ 64
#define D_ 128

#define PART_STRIDE 772         // [L, S, v:128, mxH:128, mnH:128, mxC:128, mxHC:128, mxM:128]
#define NCHUNK 64
#define CHUNK_ROWS 64
// workspace: Thi[32][16KB] | Tlo[32][16KB] | Ut[32][16KB] | part[2048][772] floats
#define TWS_BYTES (96*16384)

typedef __attribute__((ext_vector_type(8))) short bf16x8;
typedef __attribute__((ext_vector_type(4))) float f32x4;

__device__ __forceinline__ unsigned int asu(float x) { return __float_as_uint(x); }
__device__ __forceinline__ float asf(unsigned int x) { return __uint_as_float(x); }

// split-bf16 repack: fa/fb (8 consecutive fp32) -> hi/lo bf16x8 fragments
__device__ __forceinline__ void repack8(const f32x4 fa, const f32x4 fb,
                                        bf16x8* hi, bf16x8* lo) {
  union { bf16x8 v; unsigned int u[4]; } Hh, Ll;
  unsigned int a0 = asu(fa[0]), a1 = asu(fa[1]), a2 = asu(fa[2]), a3 = asu(fa[3]);
  unsigned int c0 = asu(fb[0]), c1 = asu(fb[1]), c2 = asu(fb[2]), c3 = asu(fb[3]);
  Hh.u[0] = (a1 & 0xFFFF0000u) | (a0 >> 16);
  Hh.u[1] = (a3 & 0xFFFF0000u) | (a2 >> 16);
  Hh.u[2] = (c1 & 0xFFFF0000u) | (c0 >> 16);
  Hh.u[3] = (c3 & 0xFFFF0000u) | (c2 >> 16);
  float p0 = fa[0] - asf(a0 & 0xFFFF0000u);
  float p1 = fa[1] - asf(a1 & 0xFFFF0000u);
  float p2 = fa[2] - asf(a2 & 0xFFFF0000u);
  float p3 = fa[3] - asf(a3 & 0xFFFF0000u);
  float p4 = fb[0] - asf(c0 & 0xFFFF0000u);
  float p5 = fb[1] - asf(c1 & 0xFFFF0000u);
  float p6 = fb[2] - asf(c2 & 0xFFFF0000u);
  float p7 = fb[3] - asf(c3 & 0xFFFF0000u);
  Ll.u[0] = (asu(p1) & 0xFFFF0000u) | (asu(p0) >> 16);
  Ll.u[1] = (asu(p3) & 0xFFFF0000u) | (asu(p2) >> 16);
  Ll.u[2] = (asu(p5) & 0xFFFF0000u) | (asu(p4) >> 16);
  Ll.u[3] = (asu(p7) & 0xFFFF0000u) | (asu(p6) >> 16);
  *hi = Hh.v; *lo = Ll.v;
}

// ---------------------------------------------------------------------------
// k_T: T[b,q,d] = sum_e W[d,e]*U[b,q,e]; writes PRE-SWIZZLED bf16 images:
//   Thi/Tlo: bf16 hi/lo of T,  byte (q*256+2d) ^ ((q&7)<<4)   per batch 16 KB
//   Ut:      bf16 of RAW U^T,  byte (d*128+2q) ^ ((d&7)<<4)   per batch 16 KB
// grid 256 = 32 b * 8 q-chunks, 256 threads
// ---------------------------------------------------------------------------
__global__ __launch_bounds__(256) void k_T(const float* __restrict__ U,
                                           const float* __restrict__ W,
                                           char* __restrict__ Tws) {
  __shared__ float Wl[128*132];
  __shared__ float Ul[8*128];
  const int b = blockIdx.x >> 3, qc = blockIdx.x & 7;
  const int t = threadIdx.x;
#pragma unroll
  for (int k = 0; k < 16; ++k) {
    int i = t*4 + k*1024;
    float4 wv = *(const float4*)(W + i);
    int d = i >> 7, e = i & 127;
    *(float4*)(&Wl[d*132 + e]) = wv;
  }
  {
    int i = t*4;
    int q = i >> 7, e = i & 127;
    *(float4*)(&Ul[q*128 + e]) =
        *(const float4*)(U + ((size_t)(b*Q_ + qc*8 + q))*D_ + e);
  }
  __syncthreads();
  const int d = t & 127, qhalf = t >> 7;
  char* Thi = Tws + b*16384;
  char* Tlo = Tws + 32*16384 + b*16384;
  char* Utl = Tws + 64*16384 + b*16384;
#pragma unroll
  for (int pass = 0; pass < 4; ++pass) {
    const int ql = pass*2 + qhalf;
    const int qg = qc*8 + ql;
    float acc = 0.f;
#pragma unroll
    for (int e = 0; e < 128; e += 4) {
      float4 wv = *(float4*)(&Wl[d*132 + e]);
      float4 uv = *(float4*)(&Ul[ql*128 + e]);
      acc += wv.x*uv.x + wv.y*uv.y + wv.z*uv.z + wv.w*uv.w;
    }
    unsigned int au = asu(acc);
    unsigned short hs = (unsigned short)(au >> 16);
    float lo = acc - asf(au & 0xFFFF0000u);
    unsigned short ls = (unsigned short)(asu(lo) >> 16);
    int ta = (qg*256 + 2*d) ^ ((qg & 7) << 4);
    *(unsigned short*)(Thi + ta) = hs;
    *(unsigned short*)(Tlo + ta) = ls;
    // Ut stores RAW U (bf16), NOT T — it is the B operand of c2q = P*U.
    float uval = Ul[ql*128 + d];
    int ua = (d*128 + 2*qg) ^ ((d & 7) << 4);
    *(unsigned short*)(Utl + ua) = (unsigned short)(asu(uval) >> 16);
  }
}

// ---------------------------------------------------------------------------
// k_main v12 (async-staged H): grid 2048 = 32 b * 64 chunks of 64 rows,
// 256 threads (4 waves), launch_bounds(256,3): 3 blocks/CU, VGPR cap 168.
// Stage: whole H tile (64 rows x 512B) via global_load_lds w=16 with
//   SOURCE-side inverse XOR swizzle (lds byte = r*512 + (off ^ ((r&7)<<4))).
//   All 32KB in flight at once; __syncthreads drains vmcnt -> ONE exposure.
// M preloaded to 8 f32x4 regs/thread (issued with staging).
// Phase 1: wave wv: S for rows [wv*16,+16) — A-frags from Hl, T from global L2.
// Phase 2: swapped-operand PV: C[d][p] = mfma(Ut, P^T); lane owns 2x4 consec d;
//   H from Hl, M from regs. LDS 41.3 KB.
// ---------------------------------------------------------------------------
__global__ __launch_bounds__(256, 3) void k_main(
    const float* __restrict__ H, const float* __restrict__ M,
    const int* __restrict__ tok, const char* __restrict__ Tws,
    float* __restrict__ part) {
  __shared__ __align__(16) char Hl[32768];  // H tile, 512B/row, XOR-swizzled
  __shared__ __align__(16) char Pl[8192];   // bf16 [64 p][64 q], byte = p*128+2q ^ ((p&7)<<4)
  __shared__ __align__(16) float mrow[64];
  __shared__ __align__(16) float rzrow[64];
  __shared__ __align__(16) float prow[64];
  __shared__ __align__(16) float bm[64];    // tk ? 0 : -1e38
  __shared__ int tkl[64];

  const int bid = blockIdx.x;
  const int b = bid >> 6, chunk = bid & 63;
  const int t = threadIdx.x, wv = t >> 6, l = t & 63;
  const int r15 = l & 15, g4 = l >> 4;
  const char* Thi_g = Tws + b*16384;
  const char* Tlo_g = Tws + 32*16384 + b*16384;
  const char* Utl   = Tws + 64*16384 + b*16384;
  const int rowB = b*P_ + chunk*CHUNK_ROWS;

  // ---- async stage H tile: 8 x global_load_lds(16B) per thread ----
  // dest granule gi = t + k*256 (lane-consecutive per wave: wave-uniform base
  // + lane*16 as HW requires); source address carries the inverse swizzle.
  {
    const char* Hbase = (const char*)(H + (size_t)rowB*D_);
#pragma unroll
    for (int k = 0; k < 8; ++k) {
      int gi = t + k*256;
      int r  = gi >> 5;
      int src = (r << 9) | ((((gi & 31) ^ (r & 7)) & 31) << 4);
      __builtin_amdgcn_global_load_lds(
          (const __attribute__((address_space(1))) void*)(Hbase + src),
          (__attribute__((address_space(3))) void*)(Hl + gi*16),
          16, 0, 0);
    }
  }
  if (t < 64) tkl[t] = tok[b*P_ + chunk*CHUNK_ROWS + t];

  // phase-2 constants + Ut A-fragments (L2-hot) + M register preload
  const int dbase0 = wv*16 + g4*4;
  const int dbase1 = dbase0 + 64;
  const int dA0 = wv*16 + r15, dA1 = dA0 + 64;
  bf16x8 au00 = *(const bf16x8*)(Utl + ((dA0*128 + g4*16 +  0) ^ ((dA0 & 7) << 4)));
  bf16x8 au01 = *(const bf16x8*)(Utl + ((dA0*128 + g4*16 + 64) ^ ((dA0 & 7) << 4)));
  bf16x8 au10 = *(const bf16x8*)(Utl + ((dA1*128 + g4*16 +  0) ^ ((dA1 & 7) << 4)));
  bf16x8 au11 = *(const bf16x8*)(Utl + ((dA1*128 + g4*16 + 64) ^ ((dA1 & 7) << 4)));
  f32x4 mbA[4], mbB[4];
#pragma unroll
  for (int rti = 0; rti < 4; ++rti) {
    int rt = (rti + wv) & 3;
    const float* Mrow = M + (size_t)(rowB + rt*16 + r15)*D_;
    mbA[rti] = *(const f32x4*)(Mrow + dbase0);
    mbB[rti] = *(const f32x4*)(Mrow + dbase1);
  }
  asm volatile("s_waitcnt vmcnt(0)" ::: "memory");
  __syncthreads();   // Hl ready

  // ================= phase 1: S + softmax for my 16-row tile =================
  {
    const int arow = wv*16 + r15;
    const int rsw = (arow & 7) << 4;
    f32x4 fA[4], fB[4];
#pragma unroll
    for (int ks = 0; ks < 4; ++ks) {
      int b0 = ks*128 + g4*32;
      fA[ks] = *(const f32x4*)(Hl + arow*512 + ((b0)      ^ rsw));
      fB[ks] = *(const f32x4*)(Hl + arow*512 + ((b0 + 16) ^ rsw));
    }
    bf16x8 Ah[4], Al[4];
#pragma unroll
    for (int ks = 0; ks < 4; ++ks) repack8(fA[ks], fB[ks], &Ah[ks], &Al[ks]);
    f32x4 sacc[4];
#pragma unroll
    for (int qt = 0; qt < 4; ++qt) sacc[qt] = (f32x4){0.f, 0.f, 0.f, 0.f};
#pragma unroll
    for (int ks = 0; ks < 4; ++ks) {
#pragma unroll
      for (int qt = 0; qt < 4; ++qt) {
        int q = qt*16 + r15;
        int off = (q*256 + ks*64 + g4*16) ^ ((q & 7) << 4);
        bf16x8 bh = *(const bf16x8*)(Thi_g + off);
        bf16x8 bl = *(const bf16x8*)(Tlo_g + off);
        sacc[qt] = __builtin_amdgcn_mfma_f32_16x16x32_bf16(Al[ks], bh, sacc[qt], 0, 0, 0);
        sacc[qt] = __builtin_amdgcn_mfma_f32_16x16x32_bf16(Ah[ks], bl, sacc[qt], 0, 0, 0);
        sacc[qt] = __builtin_amdgcn_mfma_f32_16x16x32_bf16(Ah[ks], bh, sacc[qt], 0, 0, 0);
      }
    }
    // row max over q (C-layout: lane holds rows g4*4+j, col qt*16+r15)
    float m[4];
#pragma unroll
    for (int j = 0; j < 4; ++j)
      m[j] = fmaxf(fmaxf(sacc[0][j], sacc[1][j]), fmaxf(sacc[2][j], sacc[3][j]));
#pragma unroll
    for (int off = 1; off <= 8; off <<= 1)
#pragma unroll
      for (int j = 0; j < 4; ++j) m[j] = fmaxf(m[j], __shfl_xor(m[j], off));
    // P = exp(S - m) -> bf16 LDS, Z per row
    float Zp[4] = {0.f, 0.f, 0.f, 0.f};
#pragma unroll
    for (int qt = 0; qt < 4; ++qt)
#pragma unroll
      for (int j = 0; j < 4; ++j) {
        float e = __expf(sacc[qt][j] - m[j]);
        Zp[j] += e;
        int p = wv*16 + g4*4 + j, q = qt*16 + r15;
        int off = (p*128 + 2*q) ^ ((p & 7) << 4);
        *(unsigned short*)(Pl + off) = (unsigned short)(asu(e) >> 16);
      }
#pragma unroll
    for (int off = 1; off <= 8; off <<= 1)
#pragma unroll
      for (int j = 0; j < 4; ++j) Zp[j] += __shfl_xor(Zp[j], off);
    if (r15 == 0) {
#pragma unroll
      for (int j = 0; j < 4; ++j) {
        mrow[wv*16 + g4*4 + j]  = m[j];
        rzrow[wv*16 + g4*4 + j] = __builtin_amdgcn_rcpf(Zp[j]);
      }
    }
  }
  __syncthreads();

  // block softmax stats over 64 rows (wave-uniform, redundant per wave)
  float m0 = mrow[l];
  float Lm = m0;
#pragma unroll
  for (int off = 1; off <= 32; off <<= 1) Lm = fmaxf(Lm, __shfl_xor(Lm, off));
  float ssum = __expf(m0 - Lm);
#pragma unroll
  for (int off = 1; off <= 32; off <<= 1) ssum += __shfl_xor(ssum, off);
  if (t < 64) {
    prow[t] = __expf(mrow[t] - Lm);
    bm[t]   = tkl[t] ? 0.f : -1.0e38f;
  }
  __syncthreads();

  // ====== phase 2 (swapped): C[d][p] = mfma(Ut, P^T); 2 d-slices per lane ====
  f32x4 v4a  = (f32x4){0.f,0.f,0.f,0.f},                 v4b  = v4a;
  f32x4 xH4a = (f32x4){-3.0e38f,-3.0e38f,-3.0e38f,-3.0e38f}, xH4b = xH4a;
  f32x4 nH4a = (f32x4){ 3.0e38f, 3.0e38f, 3.0e38f, 3.0e38f}, nH4b = nH4a;
  f32x4 xC4a = xH4a, xC4b = xH4a, xHC4a = xH4a, xHC4b = xH4a;
  f32x4 xM4a = xH4a, xM4b = xH4a;
#pragma unroll
  for (int rti = 0; rti < 4; ++rti) {
    const int rt = (rti + wv) & 3;
    const int pl = rt*16 + r15;
    const int pswz = (pl & 7) << 4;
    bf16x8 pb0 = *(bf16x8*)(Pl + ((pl*128 + g4*16 +  0) ^ pswz));
    bf16x8 pb1 = *(bf16x8*)(Pl + ((pl*128 + g4*16 + 64) ^ pswz));
    f32x4 pvA = (f32x4){0.f,0.f,0.f,0.f};
    f32x4 pvB = (f32x4){0.f,0.f,0.f,0.f};
    pvA = __builtin_amdgcn_mfma_f32_16x16x32_bf16(au00, pb0, pvA, 0, 0, 0);
    pvA = __builtin_amdgcn_mfma_f32_16x16x32_bf16(au01, pb1, pvA, 0, 0, 0);
    pvB = __builtin_amdgcn_mfma_f32_16x16x32_bf16(au10, pb0, pvB, 0, 0, 0);
    pvB = __builtin_amdgcn_mfma_f32_16x16x32_bf16(au11, pb1, pvB, 0, 0, 0);
    const int hsw = (pl & 7) << 4;
    f32x4 h4a = *(const f32x4*)(Hl + pl*512 + ((dbase0*4) ^ hsw));
    f32x4 h4b = *(const f32x4*)(Hl + pl*512 + ((dbase1*4) ^ hsw));
    f32x4 m4a = mbA[rti], m4b = mbB[rti];
    const float prw = prow[pl], rz = rzrow[pl], bmv = bm[pl];
#pragma unroll
    for (int j = 0; j < 4; ++j) {
      float cA = pvA[j] * rz;
      float cB = pvB[j] * rz;
      v4a[j]  += prw*h4a[j];                    v4b[j]  += prw*h4b[j];
      xH4a[j]  = fmaxf(xH4a[j],  h4a[j] + bmv); xH4b[j]  = fmaxf(xH4b[j],  h4b[j] + bmv);
      nH4a[j]  = fminf(nH4a[j],  h4a[j] - bmv); nH4b[j]  = fminf(nH4b[j],  h4b[j] - bmv);
      xC4a[j]  = fmaxf(xC4a[j],  cA + bmv);     xC4b[j]  = fmaxf(xC4b[j],  cB + bmv);
      xHC4a[j] = fmaxf(xHC4a[j], h4a[j]*cA + bmv); xHC4b[j] = fmaxf(xHC4b[j], h4b[j]*cB + bmv);
      xM4a[j]  = fmaxf(xM4a[j],  m4a[j] + bmv); xM4b[j]  = fmaxf(xM4b[j],  m4b[j] + bmv);
    }
  }
  // reduce over the 16 p-lanes (r15 axis)
#pragma unroll
  for (int off = 1; off <= 8; off <<= 1) {
#pragma unroll
    for (int j = 0; j < 4; ++j) {
      v4a[j]  += __shfl_xor(v4a[j], off);       v4b[j]  += __shfl_xor(v4b[j], off);
      xH4a[j]  = fmaxf(xH4a[j],  __shfl_xor(xH4a[j],  off));
      xH4b[j]  = fmaxf(xH4b[j],  __shfl_xor(xH4b[j],  off));
      nH4a[j]  = fminf(nH4a[j],  __shfl_xor(nH4a[j],  off));
      nH4b[j]  = fminf(nH4b[j],  __shfl_xor(nH4b[j],  off));
      xC4a[j]  = fmaxf(xC4a[j],  __shfl_xor(xC4a[j],  off));
      xC4b[j]  = fmaxf(xC4b[j],  __shfl_xor(xC4b[j],  off));
      xHC4a[j] = fmaxf(xHC4a[j], __shfl_xor(xHC4a[j], off));
      xHC4b[j] = fmaxf(xHC4b[j], __shfl_xor(xHC4b[j], off));
      xM4a[j]  = fmaxf(xM4a[j],  __shfl_xor(xM4a[j],  off));
      xM4b[j]  = fmaxf(xM4b[j],  __shfl_xor(xM4b[j],  off));
    }
  }
  float* pp = part + (size_t)bid*PART_STRIDE;
  if (t == 0) { pp[0] = Lm; pp[1] = ssum; }
  if (r15 == 0) {
#pragma unroll
    for (int j = 0; j < 4; ++j) {
      pp[2 + dbase0 + j]   = v4a[j];   pp[2 + dbase1 + j]   = v4b[j];
      pp[130 + dbase0 + j] = xH4a[j];  pp[130 + dbase1 + j] = xH4b[j];
      pp[258 + dbase0 + j] = nH4a[j];  pp[258 + dbase1 + j] = nH4b[j];
      pp[386 + dbase0 + j] = xC4a[j];  pp[386 + dbase1 + j] = xC4b[j];
      pp[514 + dbase0 + j] = xHC4a[j]; pp[514 + dbase1 + j] = xHC4b[j];
      pp[642 + dbase0 + j] = xM4a[j];  pp[642 + dbase1 + j] = xM4b[j];
    }
  }
}

// ---------------------------------------------------------------------------
// k_final: merge 64 chunk-partials per batch, build pooled[640], classifier
// grid 32 (one per batch), 128 threads (t = d)
// ---------------------------------------------------------------------------
__global__ __launch_bounds__(128) void k_final(const float* __restrict__ part,
                                               const float* __restrict__ Wc,
                                               float* __restrict__ out) {
  __shared__ float pooled[640];
  __shared__ float r0s[2], r1s[2];
  const int b = blockIdx.x, t = threadIdx.x;
  const float* pb = part + (size_t)b*NCHUNK*PART_STRIDE;
  float L = -3.0e38f;
#pragma unroll
  for (int c = 0; c < NCHUNK; ++c) L = fmaxf(L, pb[c*PART_STRIDE]);
  float S = 0.f, V = 0.f;
  float mh = -3.0e38f, nh = 3.0e38f, mc = -3.0e38f, mhc = -3.0e38f, mm = -3.0e38f;
#pragma unroll
  for (int c = 0; c < NCHUNK; ++c) {
    const float* p = pb + c*PART_STRIDE;
    float e = __expf(p[0] - L);
    S += p[1]*e;
    V += p[2 + t]*e;
    mh  = fmaxf(mh,  p[130 + t]);
    nh  = fminf(nh,  p[258 + t]);
    mc  = fmaxf(mc,  p[386 + t]);
    mhc = fmaxf(mhc, p[514 + t]);
    mm  = fmaxf(mm,  p[642 + t]);
  }
  float q2c = V / S;
  pooled[t]       = mh;
  pooled[128 + t] = mc;
  pooled[256 + t] = mhc;
  pooled[384 + t] = (q2c >= 0.f) ? q2c*mh : q2c*nh;
  pooled[512 + t] = mm;
  __syncthreads();
  float a0 = 0.f, a1 = 0.f;
#pragma unroll
  for (int k = t; k < 640; k += 128) {
    float pv = pooled[k];
    a0 += pv*Wc[k*2 + 0];
    a1 += pv*Wc[k*2 + 1];
  }
#pragma unroll
  for (int off = 32; off; off >>= 1) {
    a0 += __shfl_xor(a0, off);
    a1 += __shfl_xor(a1, off);
  }
  if ((t & 63) == 0) { r0s[t >> 6] = a0; r1s[t >> 6] = a1; }
  __syncthreads();
  if (t == 0) {
    out[b*2 + 0] = r0s[0] + r0s[1];
    out[b*2 + 1] = r1s[0] + r1s[1];
  }
}

// ---------------------------------------------------------------------------
extern "C" void kernel_launch(void* const* d_in, const int* in_sizes, int n_in,
                              void* d_out, int out_size, void* d_ws, size_t ws_size,
                              hipStream_t stream) {
  const float* H   = (const float*)d_in[0];
  const float* U   = (const float*)d_in[1];
  const float* M   = (const float*)d_in[2];
  const int*   tok = (const int*)d_in[3];
  const float* Wa  = (const float*)d_in[4];
  const float* Wc  = (const float*)d_in[5];
  float* out = (float*)d_out;
  char* wsc = (char*)d_ws;
  char* Tws = wsc;
  float* part = (float*)(wsc + TWS_BYTES);

  hipLaunchKernelGGL(k_T,     dim3(256),        dim3(256), 0, stream, U, Wa, Tws);
  hipLaunchKernelGGL(k_main,  dim3(B_*NCHUNK),  dim3(256), 0, stream, H, M, tok, Tws, part);
  hipLaunchKernelGGL(k_final, dim3(B_),         dim3(128), 0, stream, part, Wc, out);
}

// Round 16
// 52.055 us; speedup vs baseline: 2.0600x; 2.0600x over previous
//
#include <hip/hip_runtime.h>

#define B_ 32
#define P_ 4096
#define Q_ 64
#define D_ 128

#define PART_STRIDE 772         // [L, S, v:128, mxH:128, mnH:128, mxC:128, mxHC:128, mxM:128]
#define NCHUNK 32
#define CHUNK_ROWS 128
// workspace: Thi[32][16KB] | Tlo[32][16KB] | Ut[32][16KB] | part[1024][772] floats
#define TWS_BYTES (96*16384)

typedef __attribute__((ext_vector_type(8))) short bf16x8;
typedef __attribute__((ext_vector_type(4))) float f32x4;

__device__ __forceinline__ unsigned int asu(float x) { return __float_as_uint(x); }
__device__ __forceinline__ float asf(unsigned int x) { return __uint_as_float(x); }

// ---------------------------------------------------------------------------
// k_T: T[b,q,d] = sum_e W[d,e]*U[b,q,e]; writes PRE-SWIZZLED bf16 images:
//   Thi/Tlo: bf16 hi/lo of T,  byte (q*256+2d) ^ ((q&7)<<4)   per batch 16 KB
//   Ut:      bf16 of RAW U^T,  byte (d*128+2q) ^ ((d&7)<<4)   per batch 16 KB
// grid 256 = 32 b * 8 q-chunks, 256 threads
// ---------------------------------------------------------------------------
__global__ __launch_bounds__(256) void k_T(const float* __restrict__ U,
                                           const float* __restrict__ W,
                                           char* __restrict__ Tws) {
  __shared__ float Wl[128*132];
  __shared__ float Ul[8*128];
  const int b = blockIdx.x >> 3, qc = blockIdx.x & 7;
  const int t = threadIdx.x;
#pragma unroll
  for (int k = 0; k < 16; ++k) {
    int i = t*4 + k*1024;
    float4 wv = *(const float4*)(W + i);
    int d = i >> 7, e = i & 127;
    *(float4*)(&Wl[d*132 + e]) = wv;
  }
  {
    int i = t*4;
    int q = i >> 7, e = i & 127;
    *(float4*)(&Ul[q*128 + e]) =
        *(const float4*)(U + ((size_t)(b*Q_ + qc*8 + q))*D_ + e);
  }
  __syncthreads();
  const int d = t & 127, qhalf = t >> 7;
  char* Thi = Tws + b*16384;
  char* Tlo = Tws + 32*16384 + b*16384;
  char* Utl = Tws + 64*16384 + b*16384;
#pragma unroll
  for (int pass = 0; pass < 4; ++pass) {
    const int ql = pass*2 + qhalf;
    const int qg = qc*8 + ql;
    float acc = 0.f;
#pragma unroll
    for (int e = 0; e < 128; e += 4) {
      float4 wv = *(float4*)(&Wl[d*132 + e]);
      float4 uv = *(float4*)(&Ul[ql*128 + e]);
      acc += wv.x*uv.x + wv.y*uv.y + wv.z*uv.z + wv.w*uv.w;
    }
    unsigned int au = asu(acc);
    unsigned short hs = (unsigned short)(au >> 16);
    float lo = acc - asf(au & 0xFFFF0000u);
    unsigned short ls = (unsigned short)(asu(lo) >> 16);
    int ta = (qg*256 + 2*d) ^ ((qg & 7) << 4);
    *(unsigned short*)(Thi + ta) = hs;
    *(unsigned short*)(Tlo + ta) = ls;
    // Ut stores RAW U (bf16), NOT T — it is the B operand of c2q = P*U.
    float uval = Ul[ql*128 + d];
    int ua = (d*128 + 2*qg) ^ ((d & 7) << 4);
    *(unsigned short*)(Utl + ua) = (unsigned short)(asu(uval) >> 16);
  }
}

// ---------------------------------------------------------------------------
// k_main (round-8 best, 53.9 us): grid 1024 = 32 b * 32 chunks of 128 rows,
// 512 threads (8 waves). Thi/Tlo linearly copied to LDS; Ut frags hoisted.
// Phase 1: wave wv: S for row-tile wv (split-bf16 3-MFMA) -> P bf16 + m,1/Z.
// Phase 2: wave wv owns d-slice [wv*16,wv*16+16): 8 P-tiles x 2 MFMA;
//          fused pools + q2c per lane (single d).
// LDS: T 32K | P 16K | stats 2K = 50.5 KB -> 3 blocks/CU.
// ---------------------------------------------------------------------------
__global__ __launch_bounds__(512, 4) void k_main(
    const float* __restrict__ H, const float* __restrict__ M,
    const int* __restrict__ tok, const char* __restrict__ Tws,
    float* __restrict__ part) {
  __shared__ __align__(16) char Tl[32768];  // Thi | Tlo images (same swizzled layout)
  __shared__ __align__(16) char Pl[16384];  // bf16 [128 p][64 q], byte = p*128+2q ^ ((p&7)<<4)
  __shared__ __align__(16) float mrow[128];
  __shared__ __align__(16) float rzrow[128];
  __shared__ __align__(16) float prow[128];
  __shared__ __align__(16) float bm[128];   // tk ? 0 : -1e38
  __shared__ int tkl[128];

  const int bid = blockIdx.x;
  const int b = bid >> 5, chunk = bid & 31;
  const int t = threadIdx.x, wv = t >> 6, l = t & 63;
  const int r15 = l & 15, g4 = l >> 4;
  const char* Thi_g = Tws + b*16384;
  const char* Tlo_g = Tws + 32*16384 + b*16384;
  const char* Utl   = Tws + 64*16384 + b*16384;

  // hoisted Ut fragments for phase 2 (independent global loads, issue first)
  const int dd = wv*16 + r15;
  bf16x8 bu0 = *(const bf16x8*)(Utl + ((dd*128 +  0 + g4*16) ^ ((dd & 7) << 4)));
  bf16x8 bu1 = *(const bf16x8*)(Utl + ((dd*128 + 64 + g4*16) ^ ((dd & 7) << 4)));

  // linear coalesced copy of Thi/Tlo images into LDS (layout-preserving)
  {
    const uint4* sh = (const uint4*)Thi_g;
    const uint4* sl = (const uint4*)Tlo_g;
    uint4* dh = (uint4*)Tl;
    uint4* dl = (uint4*)(Tl + 16384);
    dh[t]       = sh[t];
    dh[t + 512] = sh[t + 512];
    dl[t]       = sl[t];
    dl[t + 512] = sl[t + 512];
  }
  if (t < 128) tkl[t] = tok[b*P_ + chunk*CHUNK_ROWS + t];
  __syncthreads();

  const int rowB = b*P_ + chunk*CHUNK_ROWS;

  // ================= phase 1: S + softmax for my 16-row tile =================
  {
    const int lrow0 = wv*16;
    const float* Arow = H + (size_t)(rowB + lrow0 + r15)*D_;
    // batch-issue all 8 global loads (constant-indexed -> registers)
    f32x4 fA[4], fB[4];
#pragma unroll
    for (int ks = 0; ks < 4; ++ks) {
      const float* ap = Arow + ks*32 + g4*8;
      fA[ks] = *(const f32x4*)(ap);
      fB[ks] = *(const f32x4*)(ap + 4);
    }
    // repack to bf16 hi/lo fragments
    union { bf16x8 v; unsigned int u[4]; } Ah[4], Al[4];
#pragma unroll
    for (int ks = 0; ks < 4; ++ks) {
      unsigned int a0 = asu(fA[ks][0]), a1 = asu(fA[ks][1]),
                   a2 = asu(fA[ks][2]), a3 = asu(fA[ks][3]);
      unsigned int c0 = asu(fB[ks][0]), c1 = asu(fB[ks][1]),
                   c2 = asu(fB[ks][2]), c3 = asu(fB[ks][3]);
      Ah[ks].u[0] = (a1 & 0xFFFF0000u) | (a0 >> 16);
      Ah[ks].u[1] = (a3 & 0xFFFF0000u) | (a2 >> 16);
      Ah[ks].u[2] = (c1 & 0xFFFF0000u) | (c0 >> 16);
      Ah[ks].u[3] = (c3 & 0xFFFF0000u) | (c2 >> 16);
      float p0 = fA[ks][0] - asf(a0 & 0xFFFF0000u);
      float p1 = fA[ks][1] - asf(a1 & 0xFFFF0000u);
      float p2 = fA[ks][2] - asf(a2 & 0xFFFF0000u);
      float p3 = fA[ks][3] - asf(a3 & 0xFFFF0000u);
      float p4 = fB[ks][0] - asf(c0 & 0xFFFF0000u);
      float p5 = fB[ks][1] - asf(c1 & 0xFFFF0000u);
      float p6 = fB[ks][2] - asf(c2 & 0xFFFF0000u);
      float p7 = fB[ks][3] - asf(c3 & 0xFFFF0000u);
      Al[ks].u[0] = (asu(p1) & 0xFFFF0000u) | (asu(p0) >> 16);
      Al[ks].u[1] = (asu(p3) & 0xFFFF0000u) | (asu(p2) >> 16);
      Al[ks].u[2] = (asu(p5) & 0xFFFF0000u) | (asu(p4) >> 16);
      Al[ks].u[3] = (asu(p7) & 0xFFFF0000u) | (asu(p6) >> 16);
    }
    f32x4 sacc[4];
#pragma unroll
    for (int qt = 0; qt < 4; ++qt) sacc[qt] = (f32x4){0.f, 0.f, 0.f, 0.f};
#pragma unroll
    for (int ks = 0; ks < 4; ++ks) {
#pragma unroll
      for (int qt = 0; qt < 4; ++qt) {
        int q = qt*16 + r15;
        int off = (q*256 + ks*64 + g4*16) ^ ((q & 7) << 4);
        bf16x8 bh = *(const bf16x8*)(Tl + off);
        bf16x8 bl = *(const bf16x8*)(Tl + 16384 + off);
        sacc[qt] = __builtin_amdgcn_mfma_f32_16x16x32_bf16(Al[ks].v, bh, sacc[qt], 0, 0, 0);
        sacc[qt] = __builtin_amdgcn_mfma_f32_16x16x32_bf16(Ah[ks].v, bl, sacc[qt], 0, 0, 0);
        sacc[qt] = __builtin_amdgcn_mfma_f32_16x16x32_bf16(Ah[ks].v, bh, sacc[qt], 0, 0, 0);
      }
    }
    // row max over q (C-layout: lane holds rows g4*4+j, col qt*16+r15)
    float m[4];
#pragma unroll
    for (int j = 0; j < 4; ++j)
      m[j] = fmaxf(fmaxf(sacc[0][j], sacc[1][j]), fmaxf(sacc[2][j], sacc[3][j]));
#pragma unroll
    for (int off = 1; off <= 8; off <<= 1)
#pragma unroll
      for (int j = 0; j < 4; ++j) m[j] = fmaxf(m[j], __shfl_xor(m[j], off));
    // P = exp(S - m) -> bf16 LDS, Z per row
    float Zp[4] = {0.f, 0.f, 0.f, 0.f};
#pragma unroll
    for (int qt = 0; qt < 4; ++qt)
#pragma unroll
      for (int j = 0; j < 4; ++j) {
        float e = __expf(sacc[qt][j] - m[j]);
        Zp[j] += e;
        int p = lrow0 + g4*4 + j, q = qt*16 + r15;
        int off = (p*128 + 2*q) ^ ((p & 7) << 4);
        *(unsigned short*)(Pl + off) = (unsigned short)(asu(e) >> 16);
      }
#pragma unroll
    for (int off = 1; off <= 8; off <<= 1)
#pragma unroll
      for (int j = 0; j < 4; ++j) Zp[j] += __shfl_xor(Zp[j], off);
    if (r15 == 0) {
#pragma unroll
      for (int j = 0; j < 4; ++j) {
        mrow[lrow0 + g4*4 + j]  = m[j];
        rzrow[lrow0 + g4*4 + j] = __builtin_amdgcn_rcpf(Zp[j]);
      }
    }
  }
  __syncthreads();

  // block softmax stats (wave-uniform, redundant per wave)
  float m0 = mrow[l], m1 = mrow[l + 64];
  float Lm = fmaxf(m0, m1);
#pragma unroll
  for (int off = 1; off <= 32; off <<= 1) Lm = fmaxf(Lm, __shfl_xor(Lm, off));
  float ssum = __expf(m0 - Lm) + __expf(m1 - Lm);
#pragma unroll
  for (int off = 1; off <= 32; off <<= 1) ssum += __shfl_xor(ssum, off);
  if (t < 128) {
    prow[t] = __expf(mrow[t] - Lm);
    bm[t]   = tkl[t] ? 0.f : -1.0e38f;
  }
  __syncthreads();

  // ================= phase 2: my d-slice over all 8 tiles =================
  float hb[8][4], mb[8][4];
#pragma unroll
  for (int rti = 0; rti < 8; ++rti) {
    const int rt = (rti + wv) & 7;
    const float* Hrow = H + (size_t)(rowB + rt*16 + g4*4)*D_ + dd;
    const float* Mrow = M + (size_t)(rowB + rt*16 + g4*4)*D_ + dd;
#pragma unroll
    for (int j = 0; j < 4; ++j) {
      hb[rti][j] = Hrow[(size_t)j*D_];
      mb[rti][j] = Mrow[(size_t)j*D_];
    }
  }

  float v = 0.f, xH = -3.0e38f, nH = 3.0e38f;
  float xC = -3.0e38f, xHC = -3.0e38f, xM = -3.0e38f;
#pragma unroll
  for (int rti = 0; rti < 8; ++rti) {
    const int rt = (rti + wv) & 7;
    f32x4 pv = (f32x4){0.f, 0.f, 0.f, 0.f};
    {
      int pr0 = rt*16 + r15;
      bf16x8 a0 = *(bf16x8*)(Pl + ((pr0*128 +  0 + g4*16) ^ ((r15 & 7) << 4)));
      bf16x8 a1 = *(bf16x8*)(Pl + ((pr0*128 + 64 + g4*16) ^ ((r15 & 7) << 4)));
      pv = __builtin_amdgcn_mfma_f32_16x16x32_bf16(a0, bu0, pv, 0, 0, 0);
      pv = __builtin_amdgcn_mfma_f32_16x16x32_bf16(a1, bu1, pv, 0, 0, 0);
    }
    const int rg = rt*16 + g4*4;
    f32x4 prw = *(const f32x4*)&prow[rg];
    f32x4 rzw = *(const f32x4*)&rzrow[rg];
    f32x4 bmw = *(const f32x4*)&bm[rg];
#pragma unroll
    for (int j = 0; j < 4; ++j) {
      const float bmax = bmw[j];
      const float bmin = -bmax;
      float h  = hb[rti][j];
      float mv = mb[rti][j];
      float c  = pv[j] * rzw[j];
      v   += prw[j]*h;
      xH   = fmaxf(xH,  h + bmax);
      nH   = fminf(nH,  h + bmin);
      xC   = fmaxf(xC,  c + bmax);
      xHC  = fmaxf(xHC, h*c + bmax);
      xM   = fmaxf(xM,  mv + bmax);
    }
  }
  // merge the 4 row-groups (g4) holding the same d
#pragma unroll
  for (int off = 16; off <= 32; off <<= 1) {
    v   += __shfl_xor(v, off);
    xH   = fmaxf(xH,  __shfl_xor(xH,  off));
    nH   = fminf(nH,  __shfl_xor(nH,  off));
    xC   = fmaxf(xC,  __shfl_xor(xC,  off));
    xHC  = fmaxf(xHC, __shfl_xor(xHC, off));
    xM   = fmaxf(xM,  __shfl_xor(xM,  off));
  }
  float* pp = part + (size_t)bid*PART_STRIDE;
  if (t == 0) { pp[0] = Lm; pp[1] = ssum; }
  if (g4 == 0) {
    pp[2 + dd]   = v;
    pp[130 + dd] = xH;
    pp[258 + dd] = nH;
    pp[386 + dd] = xC;
    pp[514 + dd] = xHC;
    pp[642 + dd] = xM;
  }
}

// ---------------------------------------------------------------------------
// k_final: merge 32 chunk-partials per batch, build pooled[640], classifier
// grid 32 (one per batch), 128 threads (t = d)
// ---------------------------------------------------------------------------
__global__ __launch_bounds__(128) void k_final(const float* __restrict__ part,
                                               const float* __restrict__ Wc,
                                               float* __restrict__ out) {
  __shared__ float pooled[640];
  __shared__ float r0s[2], r1s[2];
  const int b = blockIdx.x, t = threadIdx.x;
  const float* pb = part + (size_t)b*NCHUNK*PART_STRIDE;
  float L = -3.0e38f;
#pragma unroll
  for (int c = 0; c < NCHUNK; ++c) L = fmaxf(L, pb[c*PART_STRIDE]);
  float S = 0.f, V = 0.f;
  float mh = -3.0e38f, nh = 3.0e38f, mc = -3.0e38f, mhc = -3.0e38f, mm = -3.0e38f;
#pragma unroll
  for (int c = 0; c < NCHUNK; ++c) {
    const float* p = pb + c*PART_STRIDE;
    float e = __expf(p[0] - L);
    S += p[1]*e;
    V += p[2 + t]*e;
    mh  = fmaxf(mh,  p[130 + t]);
    nh  = fminf(nh,  p[258 + t]);
    mc  = fmaxf(mc,  p[386 + t]);
    mhc = fmaxf(mhc, p[514 + t]);
    mm  = fmaxf(mm,  p[642 + t]);
  }
  float q2c = V / S;
  pooled[t]       = mh;
  pooled[128 + t] = mc;
  pooled[256 + t] = mhc;
  pooled[384 + t] = (q2c >= 0.f) ? q2c*mh : q2c*nh;
  pooled[512 + t] = mm;
  __syncthreads();
  float a0 = 0.f, a1 = 0.f;
#pragma unroll
  for (int k = t; k < 640; k += 128) {
    float pv = pooled[k];
    a0 += pv*Wc[k*2 + 0];
    a1 += pv*Wc[k*2 + 1];
  }
#pragma unroll
  for (int off = 32; off; off >>= 1) {
    a0 += __shfl_xor(a0, off);
    a1 += __shfl_xor(a1, off);
  }
  if ((t & 63) == 0) { r0s[t >> 6] = a0; r1s[t >> 6] = a1; }
  __syncthreads();
  if (t == 0) {
    out[b*2 + 0] = r0s[0] + r0s[1];
    out[b*2 + 1] = r1s[0] + r1s[1];
  }
}

// ---------------------------------------------------------------------------
extern "C" void kernel_launch(void* const* d_in, const int* in_sizes, int n_in,
                              void* d_out, int out_size, void* d_ws, size_t ws_size,
                              hipStream_t stream) {
  const float* H   = (const float*)d_in[0];
  const float* U   = (const float*)d_in[1];
  const float* M   = (const float*)d_in[2];
  const int*   tok = (const int*)d_in[3];
  const float* Wa  = (const float*)d_in[4];
  const float* Wc  = (const float*)d_in[5];
  float* out = (float*)d_out;
  char* wsc = (char*)d_ws;
  char* Tws = wsc;
  float* part = (float*)(wsc + TWS_BYTES);

  hipLaunchKernelGGL(k_T,     dim3(256),        dim3(256), 0, stream, U, Wa, Tws);
  hipLaunchKernelGGL(k_main,  dim3(B_*NCHUNK),  dim3(512), 0, stream, H, M, tok, Tws, part);
  hipLaunchKernelGGL(k_final, dim3(B_),         dim3(128), 0, stream, part, Wc, out);
}